// Round 4
// baseline (238.376 us; speedup 1.0000x reference)
//
#include <hip/hip_runtime.h>

#define S_DIM 512
#define H_DIM 512
#define NH 256
#define TI 8
#define TJ 8

#define AS1 __attribute__((address_space(1)))
#define AS3 __attribute__((address_space(3)))

typedef _Float16 half8 __attribute__((ext_vector_type(8)));
typedef _Float16 half4 __attribute__((ext_vector_type(4)));
typedef float f32x4 __attribute__((ext_vector_type(4)));
typedef float f32x16 __attribute__((ext_vector_type(16)));

__device__ __forceinline__ int swz(int r) { return ((r & 1) << 2) | (r >> 1); }  // perm of 0..7

// ---------------- k0: fused converts ----------------
// blocks [0,512): feats fp32->f16 ; [512,768): W1 -> fragment-major f16 ; [768,832): W2 -> frag-major
__global__ __launch_bounds__(256) void convert_all_kernel(const float* __restrict__ feats,
        const float* __restrict__ W1, const float* __restrict__ W2,
        _Float16* __restrict__ f16, _Float16* __restrict__ w1L, _Float16* __restrict__ w2L) {
    int blk = blockIdx.x;
    if (blk < 512) {
        int t = blk * 256 + threadIdx.x;           // 131072 threads, 4 elems each
        float4 v = ((const float4*)feats)[t];
        half4 h;
        h.x = (_Float16)v.x; h.y = (_Float16)v.y; h.z = (_Float16)v.z; h.w = (_Float16)v.w;
        ((half4*)f16)[t] = h;
    } else if (blk < 768) {
        int t = (blk - 512) * 256 + threadIdx.x;   // 65536
        int gcb = t >> 10, n = t & 1023;
        const float* src = (n < H_DIM) ? &W1[(size_t)(gcb * 8) * H_DIM + n]
                                       : &W1[(size_t)(H_DIM + gcb * 8) * H_DIM + (n - H_DIM)];
        half8 v;
#pragma unroll
        for (int j = 0; j < 8; j++) v[j] = (_Float16)src[(size_t)j * H_DIM];
        *(half8*)&w1L[((size_t)gcb * 1024 + n) * 8] = v;
    } else {
        int t = (blk - 768) * 256 + threadIdx.x;   // 16384
        int gcb = t >> 8, n = t & 255;
        half8 v;
#pragma unroll
        for (int j = 0; j < 8; j++) v[j] = (_Float16)W2[(size_t)(gcb * 8 + j) * NH + n];
        *(half8*)&w2L[((size_t)gcb * 256 + n) * 8] = v;
    }
}

// ---------------- k1: prep GEMM  [1024 x 512] @ [512 x 1024] f16 MFMA --------------
__global__ __launch_bounds__(256) void prep_mfma_kernel(const _Float16* __restrict__ f16,
        const _Float16* __restrict__ w1L, const float* __restrict__ b1,
        _Float16* __restrict__ aH, _Float16* __restrict__ cH) {
    const int n0 = blockIdx.x * 64, m0 = blockIdx.y * 64;
    const int tid = threadIdx.x, wave = tid >> 6, lane = tid & 63;
    const int quad = lane >> 4, l16 = lane & 15;
    const int wm = wave >> 1, wn = wave & 1;
    int mrow[2], ncol[2];
#pragma unroll
    for (int mt = 0; mt < 2; mt++) mrow[mt] = m0 + wm * 32 + mt * 16 + l16;
#pragma unroll
    for (int nt = 0; nt < 2; nt++) ncol[nt] = n0 + wn * 32 + nt * 16 + l16;
    f32x4 acc[2][2];
#pragma unroll
    for (int mt = 0; mt < 2; mt++)
#pragma unroll
        for (int nt = 0; nt < 2; nt++) acc[mt][nt] = (f32x4)0.f;
#pragma unroll
    for (int ks = 0; ks < 16; ks++) {
        int gcb = ks * 4 + quad;
        half8 af[2], bf[2];
#pragma unroll
        for (int mt = 0; mt < 2; mt++)
            af[mt] = *(const half8*)&f16[(size_t)mrow[mt] * H_DIM + gcb * 8];
#pragma unroll
        for (int nt = 0; nt < 2; nt++)
            bf[nt] = *(const half8*)&w1L[((size_t)gcb * 1024 + ncol[nt]) * 8];
#pragma unroll
        for (int nt = 0; nt < 2; nt++)
#pragma unroll
            for (int mt = 0; mt < 2; mt++)
                acc[mt][nt] = __builtin_amdgcn_mfma_f32_16x16x32_f16(af[mt], bf[nt],
                                                                     acc[mt][nt], 0, 0, 0);
    }
    const bool first_half = (n0 < H_DIM);
#pragma unroll
    for (int nt = 0; nt < 2; nt++) {
        float bias = first_half ? b1[ncol[nt]] : 0.f;
#pragma unroll
        for (int mt = 0; mt < 2; mt++)
#pragma unroll
            for (int r = 0; r < 4; r++) {
                int m = m0 + wm * 32 + mt * 16 + quad * 4 + r;
                float v = acc[mt][nt][r] + bias;
                if (first_half) aH[(size_t)m * H_DIM + ncol[nt]] = (_Float16)v;
                else            cH[(size_t)m * H_DIM + (ncol[nt] - H_DIM)] = (_Float16)v;
            }
    }
}

// ---------------- k2: pair GEMM, 32x32x16 MFMA, LDS-shared af fragments ----------------
// grid (64,64,B). block 256 = 4 waves splitting N (4x64). Block M-tile = 64 pairs (8i x 8j).
// R2 structure (proven) with the MFMA shape switched to 32x32x16_f16 (2382 vs 2075 TF rate,
// and 8 instead of 16 MFMA per K-step -> fewer issue slots). Per K-step: 4 fragments
// indexed (kst in {0,1} x mt in {0,1}); wave w builds frag f=w into double-buffered LDS.
// A-layout (32x32x16): row = lane&31, k = (lane>>5)*8 + j.
// C-layout: col = lane&31, row = (reg&3) + 8*(reg>>2) + 4*(lane>>5).
__global__ __launch_bounds__(256, 4) void pair_kernel(
        const _Float16* __restrict__ aH, const _Float16* __restrict__ cH,
        const _Float16* __restrict__ w2L,
        const float* __restrict__ b2, const float* __restrict__ W3,
        const float* __restrict__ b3, float* __restrict__ out) {
    const int jt = blockIdx.x, it = blockIdx.y, b = blockIdx.z;
    const int i0 = it * TI, j0 = jt * TJ;

    __shared__ __align__(16) _Float16 sa[TI * H_DIM];     // 8 KB
    __shared__ __align__(16) _Float16 sc[TJ * H_DIM];     // 8 KB
    __shared__ __align__(16) _Float16 afb[2][4][512];     // 8 KB (2 bufs x 4 frags x 1KB)
    __shared__ float spart[4][64];                        // 1 KB

    const int tid = threadIdx.x;
    const int wave = tid >> 6, lane = tid & 63;
    const int l32 = lane & 31, hi = lane >> 5;
    const int nb = wave * 64;

    // ---- stage a rows (8) and c rows (8), swizzled: LDS slot s of row r holds
    // global chunk s ^ swz(r&7)  (DMA lane i -> LDS slot i) ----
#pragma unroll
    for (int rr0 = 0; rr0 < 2; rr0++) {
        int rr = rr0 * 4 + wave;
        int gc = lane ^ swz(rr & 7);
        __builtin_amdgcn_global_load_lds(
            (const AS1 unsigned int*)&aH[((size_t)(b * S_DIM + i0 + rr)) * H_DIM + gc * 8],
            (AS3 unsigned int*)&sa[rr * H_DIM], 16, 0, 0);
        __builtin_amdgcn_global_load_lds(
            (const AS1 unsigned int*)&cH[((size_t)(b * S_DIM + j0 + rr)) * H_DIM + gc * 8],
            (AS3 unsigned int*)&sc[rr * H_DIM], 16, 0, 0);
    }

    // this wave builds frag f = wave: kst = wave>>1 (which K16 half), mt = wave&1 (which M32)
    // 32x32 A layout: pair row p = mt*32 + l32 -> a-row il = p>>3, c-row jl = p&7
    const int kstW = wave >> 1, mtW = wave & 1;
    const int ilW = mtW * 4 + (l32 >> 3);
    const int saoffW = ilW * H_DIM;
    const int swzAW = swz(ilW);
    const int jl = l32 & 7;
    const int scoff = jl * H_DIM, swzC = swz(jl);

    f32x16 acc[2][2];
#pragma unroll
    for (int mt = 0; mt < 2; mt++)
#pragma unroll
        for (int nt = 0; nt < 2; nt++) acc[mt][nt] = (f32x16)0.f;

    // B walk: lane base = (hi*256 + nb + l32) chunk-rows; per-ks stride 4 chunks = 8192 elems.
    // within ks: kst offset 2 chunks = 4096 elems, nt offset 32 n = 256 elems.
    const _Float16* bp = &w2L[((size_t)(hi * 256 + nb + l32)) * 8];

    half8 bnxt[4];
#pragma unroll
    for (int q = 0; q < 4; q++)
        bnxt[q] = *(const half8*)&bp[(q >> 1) * 4096 + (q & 1) * 256];

    __syncthreads();   // sa/sc staged (drains DMA)

    // prologue: this wave's frag for ks=0 into buffer 0. chunk = ks*4 + kstW*2 + hi
    {
        const int chunk = kstW * 2 + hi;
        half8 va = *(const half8*)&sa[saoffW + ((chunk ^ swzAW) * 8)];
        half8 vc = *(const half8*)&sc[scoff + ((chunk ^ swzC) * 8)];
        half8 af = __builtin_elementwise_max(va + vc, (half8)(_Float16)0.f);
        *(half8*)&afb[0][wave][lane * 8] = af;
    }
    asm volatile("s_waitcnt lgkmcnt(0)" ::: "memory");
    __builtin_amdgcn_s_barrier();
    __builtin_amdgcn_sched_barrier(0);

#pragma unroll
    for (int ks = 0; ks < 16; ks++) {
        const int buf = ks & 1;
        half8 bf[4];
#pragma unroll
        for (int q = 0; q < 4; q++) bf[q] = bnxt[q];
        if (ks < 15) {
            // prefetch next B K32-chunk (stays in flight across the raw barrier)
            const _Float16* bn = bp + (size_t)8192;
#pragma unroll
            for (int q = 0; q < 4; q++)
                bnxt[q] = *(const half8*)&bn[(q >> 1) * 4096 + (q & 1) * 256];
            bp = bn;
            // build this wave's frag for ks+1 into the other buffer
            const int chunk = (ks + 1) * 4 + kstW * 2 + hi;
            half8 va = *(const half8*)&sa[saoffW + ((chunk ^ swzAW) * 8)];
            half8 vc = *(const half8*)&sc[scoff + ((chunk ^ swzC) * 8)];
            half8 af = __builtin_elementwise_max(va + vc, (half8)(_Float16)0.f);
            *(half8*)&afb[buf ^ 1][wave][lane * 8] = af;
        }
        // read all 4 fragments (kst*2+mt) for this K-step (imm offsets, conflict-free)
        half8 afr[4];
#pragma unroll
        for (int f = 0; f < 4; f++)
            afr[f] = *(const half8*)&afb[buf][f][lane * 8];
        __builtin_amdgcn_s_setprio(1);
#pragma unroll
        for (int kst = 0; kst < 2; kst++)
#pragma unroll
            for (int nt = 0; nt < 2; nt++)
#pragma unroll
                for (int mt = 0; mt < 2; mt++)
                    acc[mt][nt] = __builtin_amdgcn_mfma_f32_32x32x16_f16(
                            afr[kst * 2 + mt], bf[kst * 2 + nt], acc[mt][nt], 0, 0, 0);
        __builtin_amdgcn_s_setprio(0);
        if (ks < 15) {
            // WAR/RAW fence for afb buffers; does NOT drain vmcnt (B prefetch lives on)
            asm volatile("s_waitcnt lgkmcnt(0)" ::: "memory");
            __builtin_amdgcn_s_barrier();
            __builtin_amdgcn_sched_barrier(0);
        }
    }

    // ---- fused epilogue: h2 = relu(acc+b2); partial logit = h2 . W3 ----
    // C layout: col n = nb + nt*32 + l32; row = (r&3) + 8*(r>>2) + 4*hi; pair p = mt*32 + row
    float b2v[2], w3v[2];
#pragma unroll
    for (int nt = 0; nt < 2; nt++) {
        int n = nb + nt * 32 + l32;
        b2v[nt] = b2[n];
        w3v[nt] = W3[n];
    }
#pragma unroll
    for (int mt = 0; mt < 2; mt++) {
        float ps[16];
#pragma unroll
        for (int r = 0; r < 16; r++) {
            float s = 0.f;
#pragma unroll
            for (int nt = 0; nt < 2; nt++) {
                float v = acc[mt][nt][r] + b2v[nt];
                v = v > 0.f ? v : 0.f;
                s += v * w3v[nt];
            }
            s += __shfl_xor(s, 16, 32);
            s += __shfl_xor(s, 8, 32);
            s += __shfl_xor(s, 4, 32);
            s += __shfl_xor(s, 2, 32);
            s += __shfl_xor(s, 1, 32);
            ps[r] = s;
        }
        if (l32 == 0) {
#pragma unroll
            for (int r = 0; r < 16; r++) {
                int row = (r & 3) + 8 * (r >> 2) + 4 * hi;
                spart[wave][mt * 32 + row] = ps[r];
            }
        }
    }
    __syncthreads();
    if (tid < 64) {
        float tot = spart[0][tid] + spart[1][tid] + spart[2][tid] + spart[3][tid] + b3[0];
        float sg = 1.f / (1.f + __expf(-tot));
        int i = i0 + (tid >> 3), j = j0 + (tid & 7);
        out[(size_t)b * S_DIM * S_DIM + (size_t)i * S_DIM + j] = sg;
    }
}

extern "C" void kernel_launch(void* const* d_in, const int* in_sizes, int n_in,
                              void* d_out, int out_size, void* d_ws, size_t ws_size,
                              hipStream_t stream) {
    const float* feats = (const float*)d_in[0];
    const float* W1 = (const float*)d_in[1];
    const float* b1 = (const float*)d_in[2];
    const float* W2 = (const float*)d_in[3];
    const float* b2 = (const float*)d_in[4];
    const float* W3 = (const float*)d_in[5];
    const float* b3 = (const float*)d_in[6];
    float* out = (float*)d_out;

    const int B = in_sizes[0] / (S_DIM * H_DIM);   // = 2
    const int M = B * S_DIM;                       // 1024

    char* ws = (char*)d_ws;
    _Float16* f16  = (_Float16*)ws;                 // [1024][512] = 1 MB
    _Float16* aH   = (_Float16*)(ws + (1 << 20));   // [1024][512] = 1 MB
    _Float16* cH   = (_Float16*)(ws + (2 << 20));   // [1024][512] = 1 MB
    _Float16* w1L  = (_Float16*)(ws + (3 << 20));   // 1 MB
    _Float16* w2L  = (_Float16*)(ws + (4 << 20));   // 256 KB

    convert_all_kernel<<<832, 256, 0, stream>>>(feats, W1, W2, f16, w1L, w2L);
    prep_mfma_kernel<<<dim3(16, M / 64), 256, 0, stream>>>(f16, w1L, b1, aH, cH);
    pair_kernel<<<dim3(S_DIM / TJ, S_DIM / TI, B), 256, 0, stream>>>(aH, cH, w2L, b2, W3, b3, out);
}

// Round 5
// 196.496 us; speedup vs baseline: 1.2131x; 1.2131x over previous
//
#include <hip/hip_runtime.h>

#define S_DIM 512
#define H_DIM 512
#define NH 256
#define TI 8
#define TJ 8

#define AS1 __attribute__((address_space(1)))
#define AS3 __attribute__((address_space(3)))

typedef _Float16 half8 __attribute__((ext_vector_type(8)));
typedef _Float16 half4 __attribute__((ext_vector_type(4)));
typedef float f32x4 __attribute__((ext_vector_type(4)));

__device__ __forceinline__ int swz(int r) { return ((r & 1) << 2) | (r >> 1); }  // perm of 0..7

// ---------------- k0: fused converts ----------------
// blocks [0,512): feats fp32->f16 ; [512,768): W1 -> fragment-major f16 ; [768,832): W2 -> frag-major
__global__ __launch_bounds__(256) void convert_all_kernel(const float* __restrict__ feats,
        const float* __restrict__ W1, const float* __restrict__ W2,
        _Float16* __restrict__ f16, _Float16* __restrict__ w1L, _Float16* __restrict__ w2L) {
    int blk = blockIdx.x;
    if (blk < 512) {
        int t = blk * 256 + threadIdx.x;           // 131072 threads, 4 elems each
        float4 v = ((const float4*)feats)[t];
        half4 h;
        h.x = (_Float16)v.x; h.y = (_Float16)v.y; h.z = (_Float16)v.z; h.w = (_Float16)v.w;
        ((half4*)f16)[t] = h;
    } else if (blk < 768) {
        int t = (blk - 512) * 256 + threadIdx.x;   // 65536
        int gcb = t >> 10, n = t & 1023;
        const float* src = (n < H_DIM) ? &W1[(size_t)(gcb * 8) * H_DIM + n]
                                       : &W1[(size_t)(H_DIM + gcb * 8) * H_DIM + (n - H_DIM)];
        half8 v;
#pragma unroll
        for (int j = 0; j < 8; j++) v[j] = (_Float16)src[(size_t)j * H_DIM];
        *(half8*)&w1L[((size_t)gcb * 1024 + n) * 8] = v;
    } else {
        int t = (blk - 768) * 256 + threadIdx.x;   // 16384
        int gcb = t >> 8, n = t & 255;
        half8 v;
#pragma unroll
        for (int j = 0; j < 8; j++) v[j] = (_Float16)W2[(size_t)(gcb * 8 + j) * NH + n];
        *(half8*)&w2L[((size_t)gcb * 256 + n) * 8] = v;
    }
}

// ---------------- k1: prep GEMM  [1024 x 512] @ [512 x 1024] f16 MFMA --------------
__global__ __launch_bounds__(256) void prep_mfma_kernel(const _Float16* __restrict__ f16,
        const _Float16* __restrict__ w1L, const float* __restrict__ b1,
        _Float16* __restrict__ aH, _Float16* __restrict__ cH) {
    const int n0 = blockIdx.x * 64, m0 = blockIdx.y * 64;
    const int tid = threadIdx.x, wave = tid >> 6, lane = tid & 63;
    const int quad = lane >> 4, l16 = lane & 15;
    const int wm = wave >> 1, wn = wave & 1;
    int mrow[2], ncol[2];
#pragma unroll
    for (int mt = 0; mt < 2; mt++) mrow[mt] = m0 + wm * 32 + mt * 16 + l16;
#pragma unroll
    for (int nt = 0; nt < 2; nt++) ncol[nt] = n0 + wn * 32 + nt * 16 + l16;
    f32x4 acc[2][2];
#pragma unroll
    for (int mt = 0; mt < 2; mt++)
#pragma unroll
        for (int nt = 0; nt < 2; nt++) acc[mt][nt] = (f32x4)0.f;
#pragma unroll
    for (int ks = 0; ks < 16; ks++) {
        int gcb = ks * 4 + quad;
        half8 af[2], bf[2];
#pragma unroll
        for (int mt = 0; mt < 2; mt++)
            af[mt] = *(const half8*)&f16[(size_t)mrow[mt] * H_DIM + gcb * 8];
#pragma unroll
        for (int nt = 0; nt < 2; nt++)
            bf[nt] = *(const half8*)&w1L[((size_t)gcb * 1024 + ncol[nt]) * 8];
#pragma unroll
        for (int nt = 0; nt < 2; nt++)
#pragma unroll
            for (int mt = 0; mt < 2; mt++)
                acc[mt][nt] = __builtin_amdgcn_mfma_f32_16x16x32_f16(af[mt], bf[nt],
                                                                     acc[mt][nt], 0, 0, 0);
    }
    const bool first_half = (n0 < H_DIM);
#pragma unroll
    for (int nt = 0; nt < 2; nt++) {
        float bias = first_half ? b1[ncol[nt]] : 0.f;
#pragma unroll
        for (int mt = 0; mt < 2; mt++)
#pragma unroll
            for (int r = 0; r < 4; r++) {
                int m = m0 + wm * 32 + mt * 16 + quad * 4 + r;
                float v = acc[mt][nt][r] + bias;
                if (first_half) aH[(size_t)m * H_DIM + ncol[nt]] = (_Float16)v;
                else            cH[(size_t)m * H_DIM + (ncol[nt] - H_DIM)] = (_Float16)v;
            }
    }
}

// ---------------- k2: pair GEMM, LDS-shared af fragments, K64 barrier epochs ----------------
// grid (64,64,B). block 256 = 4 waves splitting N (4x64). Block M-tile = 64 pairs (8i x 8j).
// R2 structure (130us, best) with barrier THINNING: two K32-steps per epoch share one
// lgkmcnt(0)+s_barrier (8 barrier-phases instead of 16; 32 MFMAs of work per phase).
// Each wave builds one af fragment per substep (2/epoch) into afb[2 bufs][2 substeps][4 frags];
// all waves read back 4 frags per substep (imm-addressed, conflict-free). Raw barriers only:
// B-prefetch global loads stay in flight across them. T5 setprio around MFMA clusters.
__global__ __launch_bounds__(256, 4) void pair_kernel(
        const _Float16* __restrict__ aH, const _Float16* __restrict__ cH,
        const _Float16* __restrict__ w2L,
        const float* __restrict__ b2, const float* __restrict__ W3,
        const float* __restrict__ b3, float* __restrict__ out) {
    const int jt = blockIdx.x, it = blockIdx.y, b = blockIdx.z;
    const int i0 = it * TI, j0 = jt * TJ;

    __shared__ __align__(16) _Float16 sa[TI * H_DIM];     // 8 KB
    __shared__ __align__(16) _Float16 sc[TJ * H_DIM];     // 8 KB
    __shared__ __align__(16) _Float16 afb[2][2][4][512];  // 16 KB (2 bufs x 2 substeps x 4 frags)
    __shared__ float spart[4][64];                        // 1 KB

    const int tid = threadIdx.x;
    const int wave = tid >> 6, lane = tid & 63;
    const int quad = lane >> 4, l16 = lane & 15;
    const int nb = wave * 64;

    // ---- stage a rows (8) and c rows (8), swizzled: LDS slot s of row r holds
    // global chunk s ^ swz(r&7)  (DMA lane i -> LDS slot i) ----
#pragma unroll
    for (int rr0 = 0; rr0 < 2; rr0++) {
        int rr = rr0 * 4 + wave;
        int gc = lane ^ swz(rr & 7);
        __builtin_amdgcn_global_load_lds(
            (const AS1 unsigned int*)&aH[((size_t)(b * S_DIM + i0 + rr)) * H_DIM + gc * 8],
            (AS3 unsigned int*)&sa[rr * H_DIM], 16, 0, 0);
        __builtin_amdgcn_global_load_lds(
            (const AS1 unsigned int*)&cH[((size_t)(b * S_DIM + j0 + rr)) * H_DIM + gc * 8],
            (AS3 unsigned int*)&sc[rr * H_DIM], 16, 0, 0);
    }

    // this wave's af fragment (mt = wave): pair p = wave*16 + l16 -> a-row il, c-row jl
    const int hl = l16 >> 3;
    const int ilW = wave * 2 + hl;
    const int saoffW = ilW * H_DIM;
    const int swzAW = swz(ilW);
    const int jl = l16 & 7;
    const int scoff = jl * H_DIM, swzC = swz(jl);

    f32x4 acc[4][4];
#pragma unroll
    for (int mt = 0; mt < 4; mt++)
#pragma unroll
        for (int nt = 0; nt < 4; nt++) acc[mt][nt] = (f32x4)0.f;

    // single B pointer, walked +4*256 chunks (16 KB) per ks; nt offset = 16 chunks (256 B imm)
    const _Float16* bp = &w2L[((size_t)quad * 256 + nb + l16) * 8];

    half8 bnxt[4];
#pragma unroll
    for (int nt = 0; nt < 4; nt++) bnxt[nt] = *(const half8*)&bp[nt * 16 * 8];

    __syncthreads();   // sa/sc staged (drains DMA)

    // prologue: this wave's frags for epoch 0 (ks = 0,1) into buffer 0
#pragma unroll
    for (int s = 0; s < 2; s++) {
        const int gcb = s * 4 + quad;
        half8 va = *(const half8*)&sa[saoffW + ((gcb ^ swzAW) * 8)];
        half8 vc = *(const half8*)&sc[scoff + ((gcb ^ swzC) * 8)];
        half8 af = __builtin_elementwise_max(va + vc, (half8)(_Float16)0.f);
        *(half8*)&afb[0][s][wave][lane * 8] = af;
    }
    asm volatile("s_waitcnt lgkmcnt(0)" ::: "memory");
    __builtin_amdgcn_s_barrier();
    __builtin_amdgcn_sched_barrier(0);

#pragma unroll
    for (int e = 0; e < 8; e++) {
        const int buf = e & 1;
#pragma unroll
        for (int s = 0; s < 2; s++) {
            const int ks = e * 2 + s;
            half8 bf[4];
#pragma unroll
            for (int nt = 0; nt < 4; nt++) bf[nt] = bnxt[nt];
            if (ks < 15) {
                // prefetch next B K32-chunk (stays in flight across the raw barrier)
                const _Float16* bn = bp + (size_t)4 * 256 * 8;
#pragma unroll
                for (int nt = 0; nt < 4; nt++) bnxt[nt] = *(const half8*)&bn[nt * 16 * 8];
                bp = bn;
            }
            if (e < 7) {
                // build this wave's frag for epoch e+1, substep s, into the other buffer
                const int gcb = (2 * (e + 1) + s) * 4 + quad;
                half8 va = *(const half8*)&sa[saoffW + ((gcb ^ swzAW) * 8)];
                half8 vc = *(const half8*)&sc[scoff + ((gcb ^ swzC) * 8)];
                half8 af = __builtin_elementwise_max(va + vc, (half8)(_Float16)0.f);
                *(half8*)&afb[buf ^ 1][s][wave][lane * 8] = af;
            }
            // read all 4 fragments for this substep (imm offsets, conflict-free)
            half8 afr[4];
#pragma unroll
            for (int mt = 0; mt < 4; mt++)
                afr[mt] = *(const half8*)&afb[buf][s][mt][lane * 8];
            __builtin_amdgcn_s_setprio(1);
#pragma unroll
            for (int nt = 0; nt < 4; nt++)
#pragma unroll
                for (int mt = 0; mt < 4; mt++)
                    acc[mt][nt] = __builtin_amdgcn_mfma_f32_16x16x32_f16(afr[mt], bf[nt],
                                                                         acc[mt][nt], 0, 0, 0);
            __builtin_amdgcn_s_setprio(0);
        }
        if (e < 7) {
            // one WAR/RAW fence per epoch (covers both substeps' reads+writes);
            // does NOT drain vmcnt (B prefetch lives on)
            asm volatile("s_waitcnt lgkmcnt(0)" ::: "memory");
            __builtin_amdgcn_s_barrier();
            __builtin_amdgcn_sched_barrier(0);
        }
    }

    // ---- fused epilogue: h2 = relu(acc+b2); partial logit = h2 . W3 ----
    float b2v[4], w3v[4];
#pragma unroll
    for (int nt = 0; nt < 4; nt++) {
        int n = nb + nt * 16 + l16;
        b2v[nt] = b2[n];
        w3v[nt] = W3[n];
    }
    float ps[4][4];
#pragma unroll
    for (int mt = 0; mt < 4; mt++)
#pragma unroll
        for (int r = 0; r < 4; r++) {
            float s = 0.f;
#pragma unroll
            for (int nt = 0; nt < 4; nt++) {
                float v = acc[mt][nt][r] + b2v[nt];
                v = v > 0.f ? v : 0.f;
                s += v * w3v[nt];
            }
            ps[mt][r] = s;
        }
#pragma unroll
    for (int mt = 0; mt < 4; mt++)
#pragma unroll
        for (int r = 0; r < 4; r++) {
            float s = ps[mt][r];
            s += __shfl_xor(s, 8, 16);
            s += __shfl_xor(s, 4, 16);
            s += __shfl_xor(s, 2, 16);
            s += __shfl_xor(s, 1, 16);
            ps[mt][r] = s;
        }
    if (l16 == 0) {
#pragma unroll
        for (int mt = 0; mt < 4; mt++)
#pragma unroll
            for (int r = 0; r < 4; r++)
                spart[wave][mt * 16 + quad * 4 + r] = ps[mt][r];
    }
    __syncthreads();
    if (tid < 64) {
        float tot = spart[0][tid] + spart[1][tid] + spart[2][tid] + spart[3][tid] + b3[0];
        float sg = 1.f / (1.f + __expf(-tot));
        int i = i0 + (tid >> 3), j = j0 + (tid & 7);
        out[(size_t)b * S_DIM * S_DIM + (size_t)i * S_DIM + j] = sg;
    }
}

extern "C" void kernel_launch(void* const* d_in, const int* in_sizes, int n_in,
                              void* d_out, int out_size, void* d_ws, size_t ws_size,
                              hipStream_t stream) {
    const float* feats = (const float*)d_in[0];
    const float* W1 = (const float*)d_in[1];
    const float* b1 = (const float*)d_in[2];
    const float* W2 = (const float*)d_in[3];
    const float* b2 = (const float*)d_in[4];
    const float* W3 = (const float*)d_in[5];
    const float* b3 = (const float*)d_in[6];
    float* out = (float*)d_out;

    const int B = in_sizes[0] / (S_DIM * H_DIM);   // = 2
    const int M = B * S_DIM;                       // 1024

    char* ws = (char*)d_ws;
    _Float16* f16  = (_Float16*)ws;                 // [1024][512] = 1 MB
    _Float16* aH   = (_Float16*)(ws + (1 << 20));   // [1024][512] = 1 MB
    _Float16* cH   = (_Float16*)(ws + (2 << 20));   // [1024][512] = 1 MB
    _Float16* w1L  = (_Float16*)(ws + (3 << 20));   // 1 MB
    _Float16* w2L  = (_Float16*)(ws + (4 << 20));   // 256 KB

    convert_all_kernel<<<832, 256, 0, stream>>>(feats, W1, W2, f16, w1L, w2L);
    prep_mfma_kernel<<<dim3(16, M / 64), 256, 0, stream>>>(f16, w1L, b1, aH, cH);
    pair_kernel<<<dim3(S_DIM / TJ, S_DIM / TI, B), 256, 0, stream>>>(aH, cH, w2L, b2, W3, b3, out);
}